// Round 10
// baseline (77607.147 us; speedup 1.0000x reference)
//
#include <hip/hip_runtime.h>
#include <stdint.h>

#define NBLK 256
#define NTHR 512

typedef __attribute__((ext_vector_type(8))) short short8;
typedef __attribute__((ext_vector_type(4))) float float4_;

// ---- workspace ----
// BAR:  tree barrier counters (r5 proven layout), memset first 12288 B
// YST:  yst exchange, 2 parity x 512x64 f32 = 262144 B
// W*F:  MLP weight bf16 B-fragments (pre-converted once, redundant writes)
#define WS_BAR  0
#define WS_YST  16384
#define WS_W0F  (16384 + 262144)            // 1024 frags x 16B = 16384 B
#define WS_W1F  (WS_W0F + 16384)            // 2048 frags x 16B = 32768 B
#define WS_W2F  (WS_W1F + 32768)            // 2048 frags x 16B = 32768 B

#define LOADC(p)    __hip_atomic_load((p),  __ATOMIC_RELAXED, __HIP_MEMORY_SCOPE_SYSTEM)
#define STOREC(p,v) __hip_atomic_store((p), (v), __ATOMIC_RELAXED, __HIP_MEMORY_SCOPE_SYSTEM)

__device__ __forceinline__ unsigned short f2bf(float x) {
  union { float f; unsigned u; } v; v.f = x;
  return (unsigned short)((v.u + 0x7fffu + ((v.u >> 16) & 1u)) >> 16);
}
__device__ __forceinline__ float bf2f(unsigned short s) {
  union { unsigned u; float f; } v; v.u = ((unsigned)s) << 16; return v.f;
}
__device__ __forceinline__ float fast_exp(float x) {
  return __builtin_amdgcn_exp2f(x * 1.4426950408889634f);
}
__device__ __forceinline__ float fast_tanh(float x) {
  float e = __builtin_amdgcn_exp2f(x * 2.8853900817779268f);
  return fmaf(-2.0f, __builtin_amdgcn_rcpf(e + 1.0f), 1.0f);
}
__device__ __forceinline__ float fast_silu(float x) {
  float e = fast_exp(-x);
  return x * __builtin_amdgcn_rcpf(1.0f + e);
}

// Row-group-local barrier over 64 blocks (r5 proven): 8 leaves x 8 + root + gen.
__device__ __forceinline__ void rgbar(unsigned* bar, int h, int Rg, unsigned bn) {
  __syncthreads();
  if (threadIdx.x == 0) {
    unsigned* base = bar + 32 * (32 + Rg * 16);
    unsigned* leaf = base + 32 * (h & 7);
    unsigned* root = base + 32 * 8;
    unsigned* gen  = base + 32 * 9;
    unsigned a = __hip_atomic_fetch_add(leaf, 1u, __ATOMIC_RELAXED, __HIP_MEMORY_SCOPE_SYSTEM);
    if (a == 8u * bn - 1u) {
      unsigned r = __hip_atomic_fetch_add(root, 1u, __ATOMIC_RELAXED, __HIP_MEMORY_SCOPE_SYSTEM);
      if (r == 8u * bn - 1u) STOREC(gen, bn);
    }
    while (LOADC(gen) < bn) __builtin_amdgcn_s_sleep(1);
  }
  __syncthreads();
}

// RK combine + yst publish for the NEXT stage (SINN). kh/y are column-owned:
// every lane of qd-group holds valid k/y for rows mrow0..mrow0+3 (post-shuffle);
// only col==0 lanes publish.
template<int SINN>
__device__ __forceinline__ void rk_publish(float (&yv)[4], const float (&khv)[6][4],
                                           float dtv, int col, int mrow0, int h,
                                           float* YW) {
  float ystv[4];
  #pragma unroll
  for (int r = 0; r < 4; ++r) {
    if constexpr (SINN == 0) {
      yv[r] += dtv * (0.09646076681806523f * khv[0][r] + 0.01f * khv[1][r]
                    + 0.4798896504144996f * khv[2][r] + 1.379008574103742f * khv[3][r]
                    - 3.290069515436081f * khv[4][r] + 2.324710524099774f * khv[5][r]);
      ystv[r] = yv[r];
    } else if constexpr (SINN == 1) {
      ystv[r] = yv[r] + dtv * (0.161f * khv[0][r]);
    } else if constexpr (SINN == 2) {
      ystv[r] = yv[r] + dtv * (-0.008480655492356989f * khv[0][r]
                             + 0.335480655492357f * khv[1][r]);
    } else if constexpr (SINN == 3) {
      ystv[r] = yv[r] + dtv * (2.8971530571054935f * khv[0][r]
                             - 6.359448489975075f * khv[1][r]
                             + 4.3622954328695815f * khv[2][r]);
    } else if constexpr (SINN == 4) {
      ystv[r] = yv[r] + dtv * (5.325864828439257f * khv[0][r]
                             - 11.748883564062828f * khv[1][r]
                             + 7.4955393428898365f * khv[2][r]
                             - 0.09249506636175525f * khv[3][r]);
    } else {
      ystv[r] = yv[r] + dtv * (5.86145544294642f * khv[0][r]
                             - 12.92096931784711f * khv[1][r]
                             + 8.159367898576159f * khv[2][r]
                             - 0.071584973281401f * khv[3][r]
                             - 0.028269050394068383f * khv[4][r]);
    }
  }
  if (col == 0) {
    #pragma unroll
    for (int r = 0; r < 4; ++r)
      STOREC(&YW[(size_t)(mrow0 + r) * 64 + h], ystv[r]);
  }
}

template<int SIN>
__device__ __forceinline__ void rk_stage(
    int stepi, int sg, int h, int Rg, int R,
    float (&yv)[4], float (&khv)[6][4], float t0v, float dtv,
    unsigned char* ws, unsigned* BAR, unsigned& rseq,
    const float* logsig, const float* b0, const float* b1, const float* b2,
    unsigned short* w3lds, float* b3lds, float* intv,
    unsigned short* bounce, int* sidxp) {
  const int tid = threadIdx.x;
  const int lane = tid & 63, wv = tid >> 6;
  const int col = lane & 15, qd = lane >> 4;
  const int mrow0 = R + wv * 16 + qd * 4;      // this lane's 4 owned rows (global)

  // ---- searchsorted for this stage's time (exact f32 compare) ----
  {
    float tb = __fadd_rn(t0v, __fmul_rn((float)stepi, dtv));
    float t_cur;
    if constexpr (SIN == 0) t_cur = tb;
    else {
      constexpr float cS = (SIN == 1) ? 0.161f : (SIN == 2) ? 0.327f : (SIN == 3) ? 0.9f
                         : (SIN == 4) ? 0.9800255409045097f : 1.0f;
      t_cur = __fadd_rn(tb, __fmul_rn(cS, dtv));
    }
    if (tid < 64) {
      unsigned long long m1 = __ballot(intv[tid] < t_cur);
      if (tid == 0) *sidxp = (int)__popcll(m1);
    }
  }
  __syncthreads();
  const int idx = *sidxp;

  // ---- MLP for this wave's 16 rows (block-redundant across the Rg) ----
  // A-frag convention (verified vs proven HDNF path): lane holds [row=l&15][k=(l>>4)*8+e]
  // B-frag (verified vs proven w3lds path):           lane holds [n=l&15][k=(l>>4)*8+e]
  // C (m89):                                          reg r at [row=(l>>4)*4+r][col=l&15]
  short8 af[4];
  {
    const float* YR = (const float*)(ws + WS_YST) + (size_t)(sg & 1) * 32768;
    const short8* W0F = (const short8*)(ws + WS_W0F);
    const short8* W1F = (const short8*)(ws + WS_W1F);
    const short8* W2F = (const short8*)(ws + WS_W2F);
    unsigned short* M = bounce + wv * 512;     // wave-private [16][32] bf16 bounce

    // layer-1 A: yst rows, hi/lo bf16 split (state precision ~fp32)
    short8 a1hi[2], a1lo[2];
    #pragma unroll
    for (int kb = 0; kb < 2; ++kb) {
      union { unsigned long long u[4]; float f[8]; } yr;
      const unsigned long long* ya = (const unsigned long long*)
          (YR + (size_t)(R + wv * 16 + (lane & 15)) * 64 + kb * 32 + qd * 8);
      #pragma unroll
      for (int j = 0; j < 4; ++j) yr.u[j] = LOADC(ya + j);
      union { unsigned short s[8]; short8 v; } hi, lo;
      #pragma unroll
      for (int j = 0; j < 8; ++j) {
        unsigned short hb = f2bf(yr.f[j]);
        hi.s[j] = hb;
        lo.s[j] = f2bf(yr.f[j] - bf2f(hb));
      }
      a1hi[kb] = hi.v; a1lo[kb] = lo.v;
    }

    // layer 1: j=128 out, k=64 in
    short8 a2[4];
    #pragma unroll
    for (int kp2 = 0; kp2 < 4; ++kp2) {
      #pragma unroll
      for (int th = 0; th < 2; ++th) {
        const int t = kp2 * 2 + th;
        float4_ c; c[0] = 0.0f; c[1] = 0.0f; c[2] = 0.0f; c[3] = 0.0f;
        #pragma unroll
        for (int kb = 0; kb < 2; ++kb) {
          const short8 bf = W0F[(t * 2 + kb) * 64 + lane];
          c = __builtin_amdgcn_mfma_f32_16x16x32_bf16(a1hi[kb], bf, c, 0, 0, 0);
          c = __builtin_amdgcn_mfma_f32_16x16x32_bf16(a1lo[kb], bf, c, 0, 0, 0);
        }
        const float bv = b0[t * 16 + col];
        #pragma unroll
        for (int r = 0; r < 4; ++r)
          M[(qd * 4 + r) * 32 + th * 16 + col] = f2bf(fast_silu(c[r] + bv));
      }
      a2[kp2] = *(const short8*)&M[(lane & 15) * 32 + qd * 8];
    }

    // layer 2: 128 -> 128
    short8 a3[4];
    #pragma unroll
    for (int kp2 = 0; kp2 < 4; ++kp2) {
      #pragma unroll
      for (int th = 0; th < 2; ++th) {
        const int t = kp2 * 2 + th;
        float4_ c; c[0] = 0.0f; c[1] = 0.0f; c[2] = 0.0f; c[3] = 0.0f;
        #pragma unroll
        for (int kb = 0; kb < 4; ++kb) {
          const short8 bf = W1F[(t * 4 + kb) * 64 + lane];
          c = __builtin_amdgcn_mfma_f32_16x16x32_bf16(a2[kb], bf, c, 0, 0, 0);
        }
        const float bv = b1[t * 16 + col];
        #pragma unroll
        for (int r = 0; r < 4; ++r)
          M[(qd * 4 + r) * 32 + th * 16 + col] = f2bf(fast_silu(c[r] + bv));
      }
      a3[kp2] = *(const short8*)&M[(lane & 15) * 32 + qd * 8];
    }

    // layer 3: 128 -> 128 (hdn), output directly as GEMM A-frags
    #pragma unroll
    for (int kp2 = 0; kp2 < 4; ++kp2) {
      #pragma unroll
      for (int th = 0; th < 2; ++th) {
        const int t = kp2 * 2 + th;
        float4_ c; c[0] = 0.0f; c[1] = 0.0f; c[2] = 0.0f; c[3] = 0.0f;
        #pragma unroll
        for (int kb = 0; kb < 4; ++kb) {
          const short8 bf = W2F[(t * 4 + kb) * 64 + lane];
          c = __builtin_amdgcn_mfma_f32_16x16x32_bf16(a3[kb], bf, c, 0, 0, 0);
        }
        const float bv = b2[t * 16 + col];
        #pragma unroll
        for (int r = 0; r < 4; ++r)
          M[(qd * 4 + r) * 32 + th * 16 + col] = f2bf(fast_silu(c[r] + bv));
      }
      af[kp2] = *(const short8*)&M[(lane & 15) * 32 + qd * 8];
    }
  }

  // ---- GEMM 128 x 528 x 128 (wave wv owns m-tile wv; A in registers) ----
  float kp[4] = {0.0f, 0.0f, 0.0f, 0.0f};
  {
    const float* sp0 = logsig + (size_t)mrow0 * 34385 + (size_t)idx * 529 + 1;
    const float* sp1 = sp0 + 34385;
    const float* sp2 = sp0 + 2 * 34385;
    const float* sp3 = sp0 + 3 * 34385;
    #pragma unroll 2
    for (int nt = 0; nt < 33; ++nt) {
      const int l = nt * 16 + col;
      const float bv = b3lds[l];
      float4_ acc; acc[0] = bv; acc[1] = bv; acc[2] = bv; acc[3] = bv;
      #pragma unroll
      for (int kb = 0; kb < 4; ++kb) {
        const short8 bf = *(const short8*)(w3lds + ((nt * 4 + kb) * 64 + lane) * 8);
        acc = __builtin_amdgcn_mfma_f32_16x16x32_bf16(af[kb], bf, acc, 0, 0, 0);
      }
      kp[0] = fmaf(fast_tanh(acc[0]), sp0[l], kp[0]);
      kp[1] = fmaf(fast_tanh(acc[1]), sp1[l], kp[1]);
      kp[2] = fmaf(fast_tanh(acc[2]), sp2[l], kp[2]);
      kp[3] = fmaf(fast_tanh(acc[3]), sp3[l], kp[3]);
    }
    #pragma unroll
    for (int r = 0; r < 4; ++r) {
      float v = kp[r];
      v += __shfl_xor(v, 1); v += __shfl_xor(v, 2);
      v += __shfl_xor(v, 4); v += __shfl_xor(v, 8);
      kp[r] = v;                    // valid in ALL 16 col-lanes of each qd group
    }
  }

  // ---- k is column-local: record history, combine, publish yst for next stage ----
  #pragma unroll
  for (int r = 0; r < 4; ++r) khv[SIN][r] = kp[r];
  {
    float* YW = (float*)(ws + WS_YST) + (size_t)((sg + 1) & 1) * 32768;
    constexpr int SINN = (SIN == 5) ? 0 : SIN + 1;
    rk_publish<SINN>(yv, khv, dtv, col, mrow0, h, YW);
  }

  // ---- the ONLY barrier of the stage ----
  ++rseq; rgbar(BAR, h, Rg, rseq);
}

// __launch_bounds__(512,1): LDS (~146KB) caps at 1 block/CU anyway.
__global__ void __launch_bounds__(NTHR, 1)
rde_kernel(const float* __restrict__ ts, const float* __restrict__ logsig,
           const float* __restrict__ x0, const float* __restrict__ intervals,
           const float* __restrict__ w0, const float* __restrict__ b0,
           const float* __restrict__ w1, const float* __restrict__ b1,
           const float* __restrict__ w2, const float* __restrict__ b2,
           const float* __restrict__ w3, const float* __restrict__ b3,
           const float* __restrict__ l1w, const float* __restrict__ l1b,
           const float* __restrict__ l2w, const float* __restrict__ l2b,
           float* out, unsigned char* ws) {
  const int tid = threadIdx.x;
  const int g = blockIdx.x;
  // XCD-packed mapping (proven r3+): Rg on XCD pair {2Rg,2Rg+1}.
  const int Rg = (g >> 1) & 3;
  const int h  = ((g >> 3) << 1) | (g & 1);
  const int R  = Rg * 128;
  const int r0 = R + 2 * h;                    // epilogue-owned rows
  const int lane = tid & 63, wv = tid >> 6;
  const int col = lane & 15, qd = lane >> 4;
  const int mrow0 = R + wv * 16 + qd * 4;
  unsigned* BAR = (unsigned*)(ws + WS_BAR);
  unsigned rseq = 0;

  __shared__ __attribute__((aligned(16))) unsigned short w3lds[67584]; // 135.2 KB
  __shared__ __attribute__((aligned(16))) unsigned short bounce[8 * 512]; // 8 KB
  __shared__ float b3lds[528];
  __shared__ float intv[64];
  __shared__ float yfin[2][64];
  __shared__ float hcls[2][10];
  __shared__ int sidx;

  if (tid < 64) intv[tid] = intervals[tid];
  for (int e = tid; e < 528; e += NTHR) b3lds[e] = b3[(size_t)h * 528 + e];

  // w3 head-slice -> LDS bf16 B-fragments (proven staging)
  for (int e = tid; e < 8448; e += NTHR) {
    const int ln = e & 63, kb = (e >> 6) & 3, nt = e >> 8;
    const float* src = w3 + ((size_t)(h * 528 + nt * 16 + (ln & 15))) * 128 + kb * 32 + (ln >> 4) * 8;
    union { unsigned short s[8]; short8 v; } p;
    #pragma unroll
    for (int j = 0; j < 8; ++j) p.s[j] = f2bf(src[j]);
    *(short8*)(w3lds + e * 8) = p.v;
  }

  // MLP weight bf16 B-fragments -> WS (redundant identical writes by all blocks)
  for (int e = tid; e < 1024; e += NTHR) {     // w0: 8t x 2kb x 64
    const int ln = e & 63, kb = (e >> 6) & 1, t = e >> 7;
    const float* src = w0 + (size_t)(t * 16 + (ln & 15)) * 64 + kb * 32 + (ln >> 4) * 8;
    union { unsigned short s[8]; short8 v; } p;
    #pragma unroll
    for (int j = 0; j < 8; ++j) p.s[j] = f2bf(src[j]);
    ((short8*)(ws + WS_W0F))[e] = p.v;
  }
  for (int e = tid; e < 2048; e += NTHR) {     // w1: 8t x 4kb x 64
    const int ln = e & 63, kb = (e >> 6) & 3, t = e >> 8;
    const float* src = w1 + (size_t)(t * 16 + (ln & 15)) * 128 + kb * 32 + (ln >> 4) * 8;
    union { unsigned short s[8]; short8 v; } p;
    #pragma unroll
    for (int j = 0; j < 8; ++j) p.s[j] = f2bf(src[j]);
    ((short8*)(ws + WS_W1F))[e] = p.v;
  }
  for (int e = tid; e < 2048; e += NTHR) {     // w2: 8t x 4kb x 64
    const int ln = e & 63, kb = (e >> 6) & 3, t = e >> 8;
    const float* src = w2 + (size_t)(t * 16 + (ln & 15)) * 128 + kb * 32 + (ln >> 4) * 8;
    union { unsigned short s[8]; short8 v; } p;
    #pragma unroll
    for (int j = 0; j < 8; ++j) p.s[j] = f2bf(src[j]);
    ((short8*)(ws + WS_W2F))[e] = p.v;
  }

  // y0 = x0 @ l1w.T + l1b, column-owned: every lane computes its qd-group's 4 rows
  // for head h (redundant across the 16 col lanes — harmless, values identical).
  float yv[4], khv[6][4];
  #pragma unroll
  for (int i = 0; i < 6; ++i)
    #pragma unroll
    for (int r = 0; r < 4; ++r) khv[i][r] = 0.0f;
  {
    const float4_* wr = (const float4_*)(l1w + (size_t)h * 32);
    float4_ wv4[8];
    #pragma unroll
    for (int d = 0; d < 8; ++d) wv4[d] = wr[d];
    const float bb = l1b[h];
    #pragma unroll
    for (int r = 0; r < 4; ++r) {
      const float4_* xr = (const float4_*)(x0 + (size_t)(mrow0 + r) * 32);
      float acc = bb;
      #pragma unroll
      for (int d = 0; d < 8; ++d) {
        float4_ xv = xr[d];
        acc = fmaf(xv[0], wv4[d][0], acc); acc = fmaf(xv[1], wv4[d][1], acc);
        acc = fmaf(xv[2], wv4[d][2], acc); acc = fmaf(xv[3], wv4[d][3], acc);
      }
      yv[r] = acc;
    }
  }
  const float t0v = ts[0];
  const float dtv = (ts[128] - t0v) * (1.0f / 256.0f);
  __syncthreads();

  // publish yst_0 = y0 into buf 0, then gate
  {
    float* YW = (float*)(ws + WS_YST);
    if (col == 0) {
      #pragma unroll
      for (int r = 0; r < 4; ++r)
        STOREC(&YW[(size_t)(mrow0 + r) * 64 + h], yv[r]);
    }
  }
  ++rseq; rgbar(BAR, h, Rg, rseq);

  // ---- 256 steps x 6 stages, ONE barrier each ----
  for (int stepi = 0; stepi < 256; ++stepi) {
    const int sg = stepi * 6;
    rk_stage<0>(stepi, sg + 0, h, Rg, R, yv, khv, t0v, dtv, ws, BAR, rseq,
                logsig, b0, b1, b2, w3lds, b3lds, intv, bounce, &sidx);
    rk_stage<1>(stepi, sg + 1, h, Rg, R, yv, khv, t0v, dtv, ws, BAR, rseq,
                logsig, b0, b1, b2, w3lds, b3lds, intv, bounce, &sidx);
    rk_stage<2>(stepi, sg + 2, h, Rg, R, yv, khv, t0v, dtv, ws, BAR, rseq,
                logsig, b0, b1, b2, w3lds, b3lds, intv, bounce, &sidx);
    rk_stage<3>(stepi, sg + 3, h, Rg, R, yv, khv, t0v, dtv, ws, BAR, rseq,
                logsig, b0, b1, b2, w3lds, b3lds, intv, bounce, &sidx);
    rk_stage<4>(stepi, sg + 4, h, Rg, R, yv, khv, t0v, dtv, ws, BAR, rseq,
                logsig, b0, b1, b2, w3lds, b3lds, intv, bounce, &sidx);
    rk_stage<5>(stepi, sg + 5, h, Rg, R, yv, khv, t0v, dtv, ws, BAR, rseq,
                logsig, b0, b1, b2, w3lds, b3lds, intv, bounce, &sidx);
  }

  // ---- epilogue: final y is in YST buf 0 (published by stage 1535, gated) ----
  {
    const float* YF = (const float*)(ws + WS_YST);
    if (tid < 128) {
      const int row = tid >> 6, hh = tid & 63;
      yfin[row][hh] = LOADC(&YF[(size_t)(r0 + row) * 64 + hh]);
    }
    __syncthreads();
    if (tid < 20) {
      const int row = tid / 10, c = tid % 10;
      float acc = l2b[c];
      const float* wr = l2w + c * 64;
      #pragma unroll
      for (int i2 = 0; i2 < 64; ++i2) acc = fmaf(yfin[row][i2], wr[i2], acc);
      hcls[row][c] = acc;
    }
    __syncthreads();
    if (tid < 2) {
      const int row = tid;
      float mx = -1e30f;
      for (int c = 0; c < 10; ++c) mx = fmaxf(mx, hcls[row][c]);
      float ev[10], den = 0.0f;
      for (int c = 0; c < 10; ++c) { ev[c] = expf(hcls[row][c] - mx); den += ev[c]; }
      const float rd = 1.0f / den;
      for (int c = 0; c < 10; ++c) out[(size_t)(r0 + row) * 10 + c] = ev[c] * rd;
    }
  }
}

extern "C" void kernel_launch(void* const* d_in, const int* in_sizes, int n_in,
                              void* d_out, int out_size, void* d_ws, size_t ws_size,
                              hipStream_t stream) {
  (void)in_sizes; (void)n_in; (void)out_size; (void)ws_size;
  const float* ts        = (const float*)d_in[0];
  const float* logsig    = (const float*)d_in[1];
  const float* x0        = (const float*)d_in[2];
  const float* intervals = (const float*)d_in[3];
  const float* w0        = (const float*)d_in[4];
  const float* b0        = (const float*)d_in[5];
  const float* w1        = (const float*)d_in[6];
  const float* b1        = (const float*)d_in[7];
  const float* w2        = (const float*)d_in[8];
  const float* b2        = (const float*)d_in[9];
  const float* w3        = (const float*)d_in[10];
  const float* b3        = (const float*)d_in[11];
  const float* l1w       = (const float*)d_in[12];
  const float* l1b       = (const float*)d_in[13];
  const float* l2w       = (const float*)d_in[14];
  const float* l2b       = (const float*)d_in[15];
  float* out = (float*)d_out;
  unsigned char* ws = (unsigned char*)d_ws;

  hipMemsetAsync(d_ws, 0, 12288, stream);  // zero barrier counters

  void* args[] = { &ts, &logsig, &x0, &intervals, &w0, &b0, &w1, &b1,
                   &w2, &b2, &w3, &b3, &l1w, &l1b, &l2w, &l2b, &out, &ws };
  hipLaunchCooperativeKernel((void*)rde_kernel, dim3(NBLK), dim3(NTHR), args, 0, stream);
}